// Round 16
// baseline (327.175 us; speedup 1.0000x reference)
//
#include <hip/hip_runtime.h>
#include <hip/hip_fp16.h>
#include <math.h>
#include <type_traits>

static constexpr int THREADS = 256;
static constexpr int CAP   = 80;      // per-node neighbor capacity; in-deg ~Poisson(32), P(>=80) ~ 1e-12
static constexpr int BSH   = 9;       // dst-bucket shift: 512 nodes/bucket
static constexpr int SUBS  = 4;       // scat2 sub-windows per bucket (128 nodes each)
static constexpr int SUBN  = 128;     // scat2 nodes per sub-window
static constexpr int CAPB  = 17920;   // per-bucket pair capacity (mean 16384 + 12 sigma, mult of 4)
static constexpr int MAXB  = 256;     // max buckets supported (196 used)
static constexpr int L4WN  = 256;     // l4 nodes per window (2 windows per bucket)
static constexpr int NCH   = 8;       // l4a stream chunks per window

typedef float v2f __attribute__((ext_vector_type(2)));

// ---------------- phase 1: partition edges into dst-range bucket streams ----------------

__global__ __launch_bounds__(THREADS)
void k_part(const int* __restrict__ src, const int* __restrict__ dst,
            int* __restrict__ bcnt, int* __restrict__ pairs, int e, int nbuck) {
    __shared__ int hist[MAXB];
    __shared__ int base_s[MAXB];
    for (int i = threadIdx.x; i < nbuck; i += THREADS) hist[i] = 0;
    __syncthreads();

    int i0 = (blockIdx.x * THREADS + (int)threadIdx.x) * 8;
    int ss[8], dd[8], bb[8], rk[8];
    int c8 = 0;
    if (i0 < e) {
        c8 = min(8, e - i0);
        if (c8 == 8) {
            int4 d0 = ((const int4*)(dst + i0))[0];
            int4 d1 = ((const int4*)(dst + i0))[1];
            int4 s0 = ((const int4*)(src + i0))[0];
            int4 s1 = ((const int4*)(src + i0))[1];
            dd[0]=d0.x; dd[1]=d0.y; dd[2]=d0.z; dd[3]=d0.w;
            dd[4]=d1.x; dd[5]=d1.y; dd[6]=d1.z; dd[7]=d1.w;
            ss[0]=s0.x; ss[1]=s0.y; ss[2]=s0.z; ss[3]=s0.w;
            ss[4]=s1.x; ss[5]=s1.y; ss[6]=s1.z; ss[7]=s1.w;
        } else {
            for (int j = 0; j < c8; ++j) { dd[j] = dst[i0 + j]; ss[j] = src[i0 + j]; }
        }
        for (int j = 0; j < c8; ++j) {
            bb[j] = dd[j] >> BSH;
            rk[j] = atomicAdd(&hist[bb[j]], 1);
        }
    }
    __syncthreads();
    for (int i = threadIdx.x; i < nbuck; i += THREADS)
        base_s[i] = hist[i] ? atomicAdd(&bcnt[i], hist[i]) : 0;
    __syncthreads();
    for (int j = 0; j < c8; ++j) {
        int idx = base_s[bb[j]] + rk[j];
        if (idx < CAPB)
            pairs[(size_t)bb[j] * CAPB + idx] = ((dd[j] & ((1 << BSH) - 1)) << 17) | ss[j];
    }
}

// ---------------- phase 2: LDS-staged scatter + fused dis/xs epilogue ----------------

__global__ __launch_bounds__(THREADS)
void k_scat2(const int* __restrict__ pairs, const int* __restrict__ bcnt,
             const float* __restrict__ x, int* __restrict__ cnt, int* __restrict__ csr,
             float* __restrict__ dis, __half2* __restrict__ xs, int n) {
    __shared__ int slab[SUBN * CAP];   // 40 KB
    __shared__ int lcnt[SUBN];
    int bucket = blockIdx.x / SUBS;
    int sub    = blockIdx.x % SUBS;
    int gnode0 = (bucket << BSH) + sub * SUBN;
    if (gnode0 >= n) return;
    for (int i = threadIdx.x; i < SUBN; i += THREADS) lcnt[i] = 0;
    __syncthreads();

    int m = min(bcnt[bucket], CAPB);
    const int* pp = pairs + (size_t)bucket * CAPB;
    for (int i0 = (int)threadIdx.x * 4; i0 < m; i0 += THREADS * 4) {
        int k = min(4, m - i0);
        int v[4];
        if (k == 4) {
            int4 a = *(const int4*)(pp + i0);
            v[0] = a.x; v[1] = a.y; v[2] = a.z; v[3] = a.w;
        } else {
            for (int j = 0; j < k; ++j) v[j] = pp[i0 + j];
        }
#pragma unroll
        for (int j = 0; j < 4; ++j) {
            if (j < k) {
                int dl = v[j] >> 17;               // 9-bit local node
                if ((dl >> 7) == sub) {
                    int ln = dl & (SUBN - 1);
                    int p = atomicAdd(&lcnt[ln], 1);
                    if (p < CAP) slab[ln * CAP + p] = v[j] & 0x1FFFF;
                }
            }
        }
    }
    __syncthreads();

    size_t gbase = (size_t)gnode0 * CAP;
    for (int idx = threadIdx.x; idx < SUBN * CAP; idx += THREADS) {
        int node = gnode0 + idx / CAP;
        if (node < n) csr[gbase + idx] = slab[idx];
    }
    if (threadIdx.x < SUBN) {
        int node = gnode0 + (int)threadIdx.x;
        if (node < n) {
            int dg = min(lcnt[threadIdx.x], CAP);
            cnt[node] = dg;
            float dn = rsqrtf((float)(dg + 1));
            dis[node] = dn;
            const float* xr = x + (size_t)node * 14;
            __half2* o = xs + (size_t)node * 8;
#pragma unroll
            for (int fl = 0; fl < 7; ++fl) {
                float2 v;
                v.x = dn * xr[fl * 2];
                v.y = dn * xr[fl * 2 + 1];
                o[fl] = __float22half2_rn(v);
            }
            o[7] = __float22half2_rn(make_float2(0.f, 0.f));
        }
    }
}

// ---------------- layer-1 CSR gather (f16 rows, packed-f16 accumulate, f32 out) --------------

__global__ __launch_bounds__(THREADS)
void k_gather_l1(const __half2* __restrict__ hw, const int* __restrict__ deg,
                 const int* __restrict__ csr, const float* __restrict__ dis,
                 float* __restrict__ out, int n) {
    constexpr int SG = 4, HPL = 2, RS = 8;
    int tid = blockIdx.x * THREADS + threadIdx.x;
    int node = tid / SG;
    int fl = tid % SG;
    if (node >= n) return;
    size_t o = (size_t)node * CAP;
    int dg = deg[node];
    float dn = dis[node];

    auto loadrow = [&](int s, __half2* r) {
        union { uint2 u; __half2 h[2]; } t;
        t.u = *(const uint2*)(hw + (size_t)s * RS + fl * HPL);
        r[0] = t.h[0]; r[1] = t.h[1];
    };

    float2 self[HPL];
    {
        __half2 r[HPL];
        loadrow(node, r);
#pragma unroll
        for (int q = 0; q < HPL; ++q) {
            self[q] = __half22float2(r[q]);
            self[q].x *= dn; self[q].y *= dn;   // SELF_SCALE
        }
    }

    __half2 z = __float2half2_rn(0.f);
    __half2 c0[HPL], c1[HPL], c2[HPL], c3[HPL];
#pragma unroll
    for (int q = 0; q < HPL; ++q) { c0[q] = z; c1[q] = z; c2[q] = z; c3[q] = z; }

    int base = 0;
    for (; base + SG <= dg; base += SG) {
        int cs = csr[o + base + fl];
#pragma unroll
        for (int t = 0; t < SG; t += 4) {
            int s0 = __shfl(cs, t, SG),     s1 = __shfl(cs, t + 1, SG);
            int s2 = __shfl(cs, t + 2, SG), s3 = __shfl(cs, t + 3, SG);
            __half2 r0[HPL], r1[HPL], r2[HPL], r3[HPL];
            loadrow(s0, r0); loadrow(s1, r1); loadrow(s2, r2); loadrow(s3, r3);
#pragma unroll
            for (int q = 0; q < HPL; ++q) {
                c0[q] = __hadd2(c0[q], r0[q]);
                c1[q] = __hadd2(c1[q], r1[q]);
                c2[q] = __hadd2(c2[q], r2[q]);
                c3[q] = __hadd2(c3[q], r3[q]);
            }
        }
    }
    int rem = dg - base;
    if (rem > 0) {
        int cs = (fl < rem) ? csr[o + base + fl] : 0;
        for (int t = 0; t < rem; ++t) {
            int s = __shfl(cs, t, SG);
            __half2 r[HPL];
            loadrow(s, r);
#pragma unroll
            for (int q = 0; q < HPL; ++q) c0[q] = __hadd2(c0[q], r[q]);
        }
    }

    float* op = out + (size_t)node * 2 * RS + fl * 2 * HPL;
#pragma unroll
    for (int q = 0; q < HPL; ++q) {
        float2 v0 = __half22float2(c0[q]), v1 = __half22float2(c1[q]);
        float2 v2 = __half22float2(c2[q]), v3 = __half22float2(c3[q]);
        op[q * 2 + 0] = self[q].x + (v0.x + v1.x) + (v2.x + v3.x);
        op[q * 2 + 1] = self[q].y + (v0.y + v1.y) + (v2.y + v3.y);
    }
}

// ---------------- fp8 plane gather (SG=4, 32 B rows), f32 accumulate, f16 half-row out -------
// Pass p reads the 3.2 MB plane p (L2-resident) and writes h2 features [32p, 32p+32).

__global__ __launch_bounds__(THREADS)
void k_gather_f8h(const unsigned char* __restrict__ hw, const int* __restrict__ deg,
                  const int* __restrict__ csr, const float* __restrict__ dis,
                  const float* __restrict__ bias, __half* __restrict__ out,
                  int half, int n) {
    constexpr int SG = 4, RSB = 32;
    int tid = blockIdx.x * THREADS + threadIdx.x;
    int node = tid / SG;
    int fl = tid % SG;
    if (node >= n) return;
    size_t o = (size_t)node * CAP;
    int dg = deg[node];
    float dn = dis[node];

    auto loadrow = [&](int s, v2f* r) {
        uint2 u = *(const uint2*)(hw + (size_t)s * RSB + fl * 8);
        r[0] = __builtin_amdgcn_cvt_pk_f32_fp8(u.x, false);
        r[1] = __builtin_amdgcn_cvt_pk_f32_fp8(u.x, true);
        r[2] = __builtin_amdgcn_cvt_pk_f32_fp8(u.y, false);
        r[3] = __builtin_amdgcn_cvt_pk_f32_fp8(u.y, true);
    };

    v2f self[4];
    loadrow(node, self);

    v2f c0[4], c1[4], c2[4], c3[4];
#pragma unroll
    for (int q = 0; q < 4; ++q) { c0[q] = 0.f; c1[q] = 0.f; c2[q] = 0.f; c3[q] = 0.f; }

    int base = 0;
    for (; base + SG <= dg; base += SG) {
        int cs = csr[o + base + fl];
#pragma unroll
        for (int t = 0; t < SG; t += 4) {
            int s0 = __shfl(cs, t, SG),     s1 = __shfl(cs, t + 1, SG);
            int s2 = __shfl(cs, t + 2, SG), s3 = __shfl(cs, t + 3, SG);
            v2f r0[4], r1[4], r2[4], r3[4];
            loadrow(s0, r0); loadrow(s1, r1); loadrow(s2, r2); loadrow(s3, r3);
#pragma unroll
            for (int q = 0; q < 4; ++q) {
                c0[q] += r0[q]; c1[q] += r1[q]; c2[q] += r2[q]; c3[q] += r3[q];
            }
        }
    }
    int rem = dg - base;
    if (rem > 0) {
        int cs = (fl < rem) ? csr[o + base + fl] : 0;
        for (int t = 0; t < rem; ++t) {
            int s = __shfl(cs, t, SG);
            v2f r[4];
            loadrow(s, r);
#pragma unroll
            for (int q = 0; q < 4; ++q) c0[q] += r[q];
        }
    }

    __half* op = out + (size_t)node * 64 + half * 32 + fl * 8;
    union { __half2 h[4]; uint4 u; } p;
#pragma unroll
    for (int q = 0; q < 4; ++q) {
        v2f v = self[q] + (c0[q] + c1[q]) + (c2[q] + c3[q]);
        v *= dn;
        float2 b = ((const float2*)bias)[fl * 4 + q];
        float vx = fmaxf(v.x + b.x, 0.f);
        float vy = fmaxf(v.y + b.y, 0.f);
        p.h[q] = __floats2half2_rn(vx, vy);
    }
    *(uint4*)op = p.u;
}

// ---------------- layer-3 fp8 gather with fused W4 matvec: hw4 = dis*(h3@W4) ----------------

__global__ __launch_bounds__(THREADS)
void k_gather_l3(const unsigned char* __restrict__ hw, const int* __restrict__ deg,
                 const int* __restrict__ csr, const float* __restrict__ dis,
                 const float* __restrict__ b3, const float* __restrict__ W4,
                 float2* __restrict__ hw4, int n) {
    constexpr int SG = 4, RSB = 32;
    __shared__ float Ws4[64];   // 32 x 2
    if (threadIdx.x < 64) Ws4[threadIdx.x] = W4[threadIdx.x];
    __syncthreads();

    int tid = blockIdx.x * THREADS + threadIdx.x;
    int node = tid / SG;
    int fl = tid % SG;
    if (node >= n) return;
    size_t o = (size_t)node * CAP;
    int dg = deg[node];
    float dn = dis[node];

    auto loadrow = [&](int s, v2f* r) {
        uint2 u = *(const uint2*)(hw + (size_t)s * RSB + fl * 8);
        r[0] = __builtin_amdgcn_cvt_pk_f32_fp8(u.x, false);
        r[1] = __builtin_amdgcn_cvt_pk_f32_fp8(u.x, true);
        r[2] = __builtin_amdgcn_cvt_pk_f32_fp8(u.y, false);
        r[3] = __builtin_amdgcn_cvt_pk_f32_fp8(u.y, true);
    };

    v2f self[4];
    loadrow(node, self);

    v2f c0[4], c1[4], c2[4], c3[4];
#pragma unroll
    for (int q = 0; q < 4; ++q) { c0[q] = 0.f; c1[q] = 0.f; c2[q] = 0.f; c3[q] = 0.f; }

    int base = 0;
    for (; base + SG <= dg; base += SG) {
        int cs = csr[o + base + fl];
#pragma unroll
        for (int t = 0; t < SG; t += 4) {
            int s0 = __shfl(cs, t, SG),     s1 = __shfl(cs, t + 1, SG);
            int s2 = __shfl(cs, t + 2, SG), s3 = __shfl(cs, t + 3, SG);
            v2f r0[4], r1[4], r2[4], r3[4];
            loadrow(s0, r0); loadrow(s1, r1); loadrow(s2, r2); loadrow(s3, r3);
#pragma unroll
            for (int q = 0; q < 4; ++q) {
                c0[q] += r0[q]; c1[q] += r1[q]; c2[q] += r2[q]; c3[q] += r3[q];
            }
        }
    }
    int rem = dg - base;
    if (rem > 0) {
        int cs = (fl < rem) ? csr[o + base + fl] : 0;
        for (int t = 0; t < rem; ++t) {
            int s = __shfl(cs, t, SG);
            v2f r[4];
            loadrow(s, r);
#pragma unroll
            for (int q = 0; q < 4; ++q) c0[q] += r[q];
        }
    }

    float p0 = 0.f, p1 = 0.f;
#pragma unroll
    for (int q = 0; q < 4; ++q) {
        v2f v = self[q] + (c0[q] + c1[q]) + (c2[q] + c3[q]);
        v *= dn;
        float2 b = ((const float2*)b3)[fl * 4 + q];
        float vx = fmaxf(v.x + b.x, 0.f);
        float vy = fmaxf(v.y + b.y, 0.f);
        int f = 8 * fl + 2 * q;               // feature index of vx
        p0 += vx * Ws4[f * 2 + 0] + vy * Ws4[(f + 1) * 2 + 0];
        p1 += vx * Ws4[f * 2 + 1] + vy * Ws4[(f + 1) * 2 + 1];
    }
    p0 += __shfl_xor(p0, 1, SG); p0 += __shfl_xor(p0, 2, SG);
    p1 += __shfl_xor(p1, 1, SG); p1 += __shfl_xor(p1, 2, SG);
    if (fl == 0) hw4[node] = make_float2(p0 * dn, p1 * dn);
}

// ---------------- layer-4 phase A: chunked stream -> per-(window,chunk) partials ------------

__global__ __launch_bounds__(THREADS)
void k_l4a(const int* __restrict__ pairs, const int* __restrict__ bcnt,
           const float2* __restrict__ hw4, float2* __restrict__ part, int n) {
    __shared__ float accx[L4WN], accy[L4WN];
    int w     = blockIdx.x / NCH;
    int chunk = blockIdx.x % NCH;
    int bucket = w >> 1;
    int sub    = w & 1;
    int gnode0 = (bucket << BSH) + sub * L4WN;
    if (gnode0 >= n) return;
    for (int i = threadIdx.x; i < L4WN; i += THREADS) { accx[i] = 0.f; accy[i] = 0.f; }
    __syncthreads();

    int m = min(bcnt[bucket], CAPB);
    int c0 = ((chunk * m) / NCH) & ~3;
    int c1 = (chunk == NCH - 1) ? m : (((chunk + 1) * m) / NCH) & ~3;
    const int* pp = pairs + (size_t)bucket * CAPB;
    for (int i0 = c0 + (int)threadIdx.x * 4; i0 < c1; i0 += THREADS * 4) {
        int k = min(4, c1 - i0);
        int v[4];
        if (k == 4) {
            int4 a = *(const int4*)(pp + i0);
            v[0] = a.x; v[1] = a.y; v[2] = a.z; v[3] = a.w;
        } else {
            for (int j = 0; j < k; ++j) v[j] = pp[i0 + j];
        }
        float2 wv[4]; int ln[4]; bool ok[4];
#pragma unroll
        for (int j = 0; j < 4; ++j) {
            int dl = v[j] >> 17;
            ok[j] = (j < k) && ((dl >> 8) == sub);
            ln[j] = dl & (L4WN - 1);
            int s = ok[j] ? (v[j] & 0x1FFFF) : 0;
            wv[j] = hw4[s];
        }
#pragma unroll
        for (int j = 0; j < 4; ++j) {
            if (ok[j]) {
                atomicAdd(&accx[ln[j]], wv[j].x);
                atomicAdd(&accy[ln[j]], wv[j].y);
            }
        }
    }
    __syncthreads();

    float2* op = part + ((size_t)w * NCH + chunk) * L4WN;
    for (int i = threadIdx.x; i < L4WN; i += THREADS)
        op[i] = make_float2(accx[i], accy[i]);
}

// ---------------- layer-4 phase B: sum partials, finalize h4, run-combined pool -------------

__global__ __launch_bounds__(THREADS)
void k_l4b(const float2* __restrict__ part, const float2* __restrict__ hw4,
           const float* __restrict__ dis, const float* __restrict__ b4,
           const int* __restrict__ batch, float* __restrict__ sums,
           float* __restrict__ cnts, int n) {
    __shared__ float h0s[L4WN], h1s[L4WN];
    int w = blockIdx.x;
    int bucket = w >> 1;
    int sub    = w & 1;
    int gnode0 = (bucket << BSH) + sub * L4WN;
    if (gnode0 >= n) return;
    int i = threadIdx.x;                 // THREADS == L4WN
    int node = gnode0 + i;
    if (node < n) {
        const float2* pp = part + (size_t)w * NCH * L4WN;
        float ax = 0.f, ay = 0.f;
#pragma unroll
        for (int ch = 0; ch < NCH; ++ch) {
            float2 p = pp[ch * L4WN + i];
            ax += p.x; ay += p.y;
        }
        float2 self = hw4[node];
        float dn = dis[node];
        h0s[i] = (self.x + ax) * dn + b4[0];
        h1s[i] = (self.y + ay) * dn + b4[1];
    }
    __syncthreads();

    if (threadIdx.x < L4WN / 8) {
        int i0 = threadIdx.x * 8;
        int nvalid = min(gnode0 + L4WN, n) - gnode0;
        int end = min(i0 + 8, nvalid);
        if (i0 < nvalid) {
            int g = batch[gnode0 + i0];
            float v0 = 0.f, v1 = 0.f, c = 0.f;
            for (int q = i0; q < end; ++q) {
                int gi = batch[gnode0 + q];
                if (gi != g) {
                    atomicAdd(&sums[g * 2 + 0], v0);
                    atomicAdd(&sums[g * 2 + 1], v1);
                    atomicAdd(&cnts[g], c);
                    g = gi; v0 = 0.f; v1 = 0.f; c = 0.f;
                }
                v0 += h0s[q];
                v1 += h1s[q];
                c += 1.0f;
            }
            atomicAdd(&sums[g * 2 + 0], v0);
            atomicAdd(&sums[g * 2 + 1], v1);
            atomicAdd(&cnts[g], c);
        }
    }
}

__global__ void k_logsoftmax(const float* __restrict__ sums, const float* __restrict__ cnts,
                             float* __restrict__ out, int ng) {
    int g = blockIdx.x * blockDim.x + threadIdx.x;
    if (g >= ng) return;
    float c = fmaxf(cnts[g], 1.0f);
    float p0 = sums[g * 2 + 0] / c;
    float p1 = sums[g * 2 + 1] / c;
    float m = fmaxf(p0, p1);
    float l = m + logf(expf(p0 - m) + expf(p1 - m));
    out[g * 2 + 0] = p0 - l;
    out[g * 2 + 1] = p1 - l;
}

// ---------------- register-blocked GEMM: 2 nodes x 4 cols per thread ----------------
// OUTM: 0 = f32, 1 = f16, 2 = fp8. SPLIT8: fp8 output into two n*32 feature planes.

template<int KW, int K, int KSTR, int FOUT, bool EPI_BIAS_RELU, int OUTM, bool SPLIT8, typename IN_T>
__global__ __launch_bounds__(THREADS)
void k_gemm_rb(const IN_T* __restrict__ in, const float* __restrict__ W,
               const float* __restrict__ dis, const float* __restrict__ bias,
               void* __restrict__ outv, int n) {
    constexpr int CG = FOUT / 4;
    constexpr bool IN_HALF = std::is_same<IN_T, __half>::value;
    constexpr int CH = IN_HALF ? 8 : 4;   // k-chunk per vector load
    __shared__ float Ws[K * FOUT];
    for (int i = threadIdx.x; i < K * FOUT; i += THREADS) {
        int r = i / FOUT;
        Ws[i] = (r < KW) ? W[i] : 0.0f;
    }
    __syncthreads();
    int gid = blockIdx.x * THREADS + threadIdx.x;
    int pair = gid / CG, cg = gid % CG;
    int node0 = pair * 2;
    if (node0 >= n) return;
    bool two = (node0 + 1 < n);
    const IN_T* r0 = in + (size_t)node0 * KSTR;
    const IN_T* r1 = two ? in + (size_t)(node0 + 1) * KSTR : r0;
    const float4* Wf4 = (const float4*)Ws;
    float4 acc0 = {0.f, 0.f, 0.f, 0.f}, acc1 = {0.f, 0.f, 0.f, 0.f};
#pragma unroll
    for (int k0 = 0; k0 < K / CH; ++k0) {
        float xv0[CH], xv1[CH];
        if constexpr (IN_HALF) {
            union { uint4 u; __half2 h[4]; } t0, t1;
            t0.u = ((const uint4*)r0)[k0];
            t1.u = ((const uint4*)r1)[k0];
#pragma unroll
            for (int i = 0; i < 4; ++i) {
                float2 g0 = __half22float2(t0.h[i]);
                float2 g1 = __half22float2(t1.h[i]);
                xv0[2 * i] = g0.x; xv0[2 * i + 1] = g0.y;
                xv1[2 * i] = g1.x; xv1[2 * i + 1] = g1.y;
            }
        } else {
            float4 a0 = ((const float4*)r0)[k0];
            float4 a1 = ((const float4*)r1)[k0];
#pragma unroll
            for (int i = 0; i < 4; ++i) { xv0[i] = (&a0.x)[i]; xv1[i] = (&a1.x)[i]; }
        }
#pragma unroll
        for (int kk = 0; kk < CH; ++kk) {
            float4 wv = Wf4[(k0 * CH + kk) * CG + cg];
            float a = xv0[kk], b = xv1[kk];
            acc0.x += a * wv.x; acc0.y += a * wv.y; acc0.z += a * wv.z; acc0.w += a * wv.w;
            acc1.x += b * wv.x; acc1.y += b * wv.y; acc1.z += b * wv.z; acc1.w += b * wv.w;
        }
    }
    float dn0 = dis[node0];
    float dn1 = two ? dis[node0 + 1] : 0.f;
    acc0.x *= dn0; acc0.y *= dn0; acc0.z *= dn0; acc0.w *= dn0;
    acc1.x *= dn1; acc1.y *= dn1; acc1.z *= dn1; acc1.w *= dn1;
    if (EPI_BIAS_RELU) {
        float4 bv = ((const float4*)bias)[cg];
        acc0.x = fmaxf(acc0.x + bv.x, 0.f); acc0.y = fmaxf(acc0.y + bv.y, 0.f);
        acc0.z = fmaxf(acc0.z + bv.z, 0.f); acc0.w = fmaxf(acc0.w + bv.w, 0.f);
        acc1.x = fmaxf(acc1.x + bv.x, 0.f); acc1.y = fmaxf(acc1.y + bv.y, 0.f);
        acc1.z = fmaxf(acc1.z + bv.z, 0.f); acc1.w = fmaxf(acc1.w + bv.w, 0.f);
    }
    if constexpr (OUTM == 2) {
        unsigned char* ob = (unsigned char*)outv;
        size_t rowb = SPLIT8 ? 32 : FOUT;
        size_t base = SPLIT8 ? ((size_t)(cg >> 3) * ((size_t)n * 32) + (size_t)(cg & 7) * 4)
                             : ((size_t)cg * 4);
        int w0 = 0;
        w0 = __builtin_amdgcn_cvt_pk_fp8_f32(acc0.x, acc0.y, w0, false);
        w0 = __builtin_amdgcn_cvt_pk_fp8_f32(acc0.z, acc0.w, w0, true);
        *(unsigned*)(ob + base + (size_t)node0 * rowb) = (unsigned)w0;
        if (two) {
            int w1 = 0;
            w1 = __builtin_amdgcn_cvt_pk_fp8_f32(acc1.x, acc1.y, w1, false);
            w1 = __builtin_amdgcn_cvt_pk_fp8_f32(acc1.z, acc1.w, w1, true);
            *(unsigned*)(ob + base + (size_t)(node0 + 1) * rowb) = (unsigned)w1;
        }
    } else if constexpr (OUTM == 1) {
        __half* out = (__half*)outv;
        union { __half2 h[2]; uint2 u; } p0, p1;
        p0.h[0] = __floats2half2_rn(acc0.x, acc0.y);
        p0.h[1] = __floats2half2_rn(acc0.z, acc0.w);
        *(uint2*)(out + (size_t)node0 * FOUT + cg * 4) = p0.u;
        if (two) {
            p1.h[0] = __floats2half2_rn(acc1.x, acc1.y);
            p1.h[1] = __floats2half2_rn(acc1.z, acc1.w);
            *(uint2*)(out + (size_t)(node0 + 1) * FOUT + cg * 4) = p1.u;
        }
    } else {
        float* out = (float*)outv;
        ((float4*)(out + (size_t)node0 * FOUT))[cg] = acc0;
        if (two) ((float4*)(out + (size_t)(node0 + 1) * FOUT))[cg] = acc1;
    }
}

// ---------------- launch ----------------

static inline int nblk(long long t) { return (int)((t + THREADS - 1) / THREADS); }

extern "C" void kernel_launch(void* const* d_in, const int* in_sizes, int n_in,
                              void* d_out, int out_size, void* d_ws, size_t ws_size,
                              hipStream_t stream) {
    const float* x     = (const float*)d_in[0];
    const int*   ei    = (const int*)d_in[1];
    const int*   batch = (const int*)d_in[2];
    const float* W1 = (const float*)d_in[4];
    const float* b1 = (const float*)d_in[5];
    const float* W2 = (const float*)d_in[6];
    const float* b2 = (const float*)d_in[7];
    const float* W3 = (const float*)d_in[8];
    const float* b3 = (const float*)d_in[9];
    const float* W4 = (const float*)d_in[10];
    const float* b4 = (const float*)d_in[11];

    const int n  = in_sizes[0] / 14;
    const int e  = in_sizes[1] / 2;
    const int ng = out_size / 2;
    const int* src = ei;
    const int* dst = ei + e;
    const int nbuck = (n + (1 << BSH) - 1) >> BSH;   // 196 for n=100000
    const int nwin  = nbuck * 2;

    char* ws = (char*)d_ws;
    size_t off_b = 0;
    auto alloc = [&](size_t bytes) -> char* {
        char* p = ws + off_b;
        off_b = (off_b + bytes + 255) & ~(size_t)255;
        return p;
    };
    int*     cnt  = (int*)alloc((size_t)n * 4);                 // in-degree (written by k_scat2)
    char*    zbase = alloc((size_t)MAXB * 4);                   // bcnt | sums | cnts -> one memset
    int*     bcnt = (int*)zbase;
    float*   sums = (float*)alloc((size_t)ng * 2 * 4);
    float*   cnts = (float*)alloc((size_t)ng * 4);
    size_t   zspan = (size_t)((char*)cnts + (size_t)ng * 4 - zbase);
    float*   dis  = (float*)alloc((size_t)n * 4);
    int*     csr  = (int*)alloc((size_t)n * CAP * 4);           // 32 MB CAP-strided rows
    int*     pairs= (int*)alloc((size_t)nbuck * CAPB * 4);      // 14 MB; LIVE until k_l4a
    __half2* xs16 = (__half2*)alloc((size_t)n * 8 * 4);         // n x 16 f16 (3.2 MB, L2-fit)
    float*   agg1 = (float*)alloc((size_t)n * 16 * 4);          // n x 16 f32
    __half*  hbuf16 = (__half*)alloc((size_t)n * 64 * 2);       // h1/h2 f16 (reused)
    unsigned char* hw8 = (unsigned char*)alloc((size_t)n * 64); // hw2' fp8 2 planes / hw3' fp8
    float*   hw4  = (float*)alloc((size_t)n * 2 * 4);
    float2*  part = (float2*)alloc((size_t)nwin * NCH * L4WN * 8);  // 6.4 MB l4 partials
    (void)ws_size; (void)n_in;

    // --- zero bcnt+sums+cnts; build pairs; windowed scatter (+dis/xs fused) ---
    hipMemsetAsync(zbase, 0, zspan, stream);
    k_part<<<nblk(((long long)e + 7) / 8), THREADS, 0, stream>>>(src, dst, bcnt, pairs, e, nbuck);
    k_scat2<<<nbuck * SUBS, THREADS, 0, stream>>>(pairs, bcnt, x, cnt, csr, dis, xs16, n);

    // --- Layer 1 (pre-aggregate at F=16 f16): SG=4; GEMM out f16 ---
    k_gather_l1<<<nblk((long long)n * 4), THREADS, 0, stream>>>(
        xs16, cnt, csr, dis, agg1, n);
    k_gemm_rb<14, 16, 16, 64, true, 1, false, float><<<nblk((long long)(n / 2 + 1) * 16), THREADS, 0, stream>>>(
        agg1, W1, dis, b1, hbuf16, n);                                // h1 f16

    // --- Layer 2: GEMM f16 in / fp8 out (2 planes); 2 plane-gather passes (L2-resident) ---
    k_gemm_rb<64, 64, 64, 64, false, 2, true, __half><<<nblk((long long)(n / 2 + 1) * 16), THREADS, 0, stream>>>(
        hbuf16, W2, dis, nullptr, hw8, n);                            // hw2' fp8: plane0 | plane1
    k_gather_f8h<<<nblk((long long)n * 4), THREADS, 0, stream>>>(
        hw8, cnt, csr, dis, b2, hbuf16, 0, n);                        // h2 features [0,32)
    k_gather_f8h<<<nblk((long long)n * 4), THREADS, 0, stream>>>(
        hw8 + (size_t)n * 32, cnt, csr, dis, b2 + 32, hbuf16, 1, n);  // h2 features [32,64)

    // --- Layer 3: GEMM f16 in / fp8 out; fp8 gather with fused W4 matvec ---
    k_gemm_rb<64, 64, 64, 32, false, 2, false, __half><<<nblk((long long)(n / 2 + 1) * 8), THREADS, 0, stream>>>(
        hbuf16, W3, dis, nullptr, hw8, n);                            // hw3' fp8 (32 B rows, 3.2 MB)
    k_gather_l3<<<nblk((long long)n * 4), THREADS, 0, stream>>>(
        hw8, cnt, csr, dis, b3, W4, (float2*)hw4, n);                 // hw4 = dis*(h3@W4)

    // --- Layer 4: chunked partials (3136 blocks) -> finalize+pool (392 blocks) ---
    k_l4a<<<nwin * NCH, THREADS, 0, stream>>>(
        pairs, bcnt, (const float2*)hw4, part, n);
    k_l4b<<<nwin, THREADS, 0, stream>>>(
        part, (const float2*)hw4, dis, b4, batch, sums, cnts, n);
    k_logsoftmax<<<nblk(ng), THREADS, 0, stream>>>(sums, cnts, (float*)d_out, ng);
}

// Round 17
// 309.482 us; speedup vs baseline: 1.0572x; 1.0572x over previous
//
#include <hip/hip_runtime.h>
#include <hip/hip_fp16.h>
#include <math.h>
#include <type_traits>

static constexpr int THREADS = 256;
static constexpr int CAP   = 80;      // per-node neighbor capacity; in-deg ~Poisson(32), P(>=80) ~ 1e-12
static constexpr int BSH   = 9;       // dst-bucket shift: 512 nodes/bucket
static constexpr int SUBS  = 4;       // scat2 sub-windows per bucket (128 nodes each)
static constexpr int SUBN  = 128;     // scat2 nodes per sub-window
static constexpr int CAPB  = 17920;   // per-bucket pair capacity (mean 16384 + 12 sigma, mult of 4)
static constexpr int MAXB  = 256;     // max buckets supported (196 used)
static constexpr int L4WN  = 256;     // l4 nodes per window (2 windows per bucket)
static constexpr int NCH   = 8;       // l4a stream chunks per window

typedef float v2f __attribute__((ext_vector_type(2)));

// ---------------- phase 1: partition edges into dst-range bucket streams ----------------
// Per-WAVE replicated histogram (4 copies) kills cross-wave same-address LDS atomic
// contention; merge computes per-copy bases with one global atomic per bucket.

__global__ __launch_bounds__(THREADS)
void k_part(const int* __restrict__ src, const int* __restrict__ dst,
            int* __restrict__ bcnt, int* __restrict__ pairs, int e, int nbuck) {
    __shared__ int hist[4][MAXB];     // 4 KB
    __shared__ int base_s[4][MAXB];   // 4 KB
    int cp = threadIdx.x >> 6;        // wave id 0..3
    for (int i = threadIdx.x; i < 4 * MAXB; i += THREADS) ((int*)hist)[i] = 0;
    __syncthreads();

    int i0 = (blockIdx.x * THREADS + (int)threadIdx.x) * 8;
    int ss[8], dd[8], bb[8], rk[8];
    int c8 = 0;
    if (i0 < e) {
        c8 = min(8, e - i0);
        if (c8 == 8) {
            int4 d0 = ((const int4*)(dst + i0))[0];
            int4 d1 = ((const int4*)(dst + i0))[1];
            int4 s0 = ((const int4*)(src + i0))[0];
            int4 s1 = ((const int4*)(src + i0))[1];
            dd[0]=d0.x; dd[1]=d0.y; dd[2]=d0.z; dd[3]=d0.w;
            dd[4]=d1.x; dd[5]=d1.y; dd[6]=d1.z; dd[7]=d1.w;
            ss[0]=s0.x; ss[1]=s0.y; ss[2]=s0.z; ss[3]=s0.w;
            ss[4]=s1.x; ss[5]=s1.y; ss[6]=s1.z; ss[7]=s1.w;
        } else {
            for (int j = 0; j < c8; ++j) { dd[j] = dst[i0 + j]; ss[j] = src[i0 + j]; }
        }
        for (int j = 0; j < c8; ++j) {
            bb[j] = dd[j] >> BSH;
            rk[j] = atomicAdd(&hist[cp][bb[j]], 1);
        }
    }
    __syncthreads();
    for (int b = threadIdx.x; b < nbuck; b += THREADS) {
        int h0 = hist[0][b], h1 = hist[1][b], h2 = hist[2][b], h3 = hist[3][b];
        int tot = h0 + h1 + h2 + h3;
        int gb = tot ? atomicAdd(&bcnt[b], tot) : 0;
        base_s[0][b] = gb;
        base_s[1][b] = gb + h0;
        base_s[2][b] = gb + h0 + h1;
        base_s[3][b] = gb + h0 + h1 + h2;
    }
    __syncthreads();
    for (int j = 0; j < c8; ++j) {
        int idx = base_s[cp][bb[j]] + rk[j];
        if (idx < CAPB)
            pairs[(size_t)bb[j] * CAPB + idx] = ((dd[j] & ((1 << BSH) - 1)) << 17) | ss[j];
    }
}

// ---------------- phase 2: LDS-staged scatter + fused dis/xs epilogue ----------------

__global__ __launch_bounds__(THREADS)
void k_scat2(const int* __restrict__ pairs, const int* __restrict__ bcnt,
             const float* __restrict__ x, int* __restrict__ cnt, int* __restrict__ csr,
             float* __restrict__ dis, __half2* __restrict__ xs, int n) {
    __shared__ int slab[SUBN * CAP];   // 40 KB
    __shared__ int lcnt[SUBN];
    int bucket = blockIdx.x / SUBS;
    int sub    = blockIdx.x % SUBS;
    int gnode0 = (bucket << BSH) + sub * SUBN;
    if (gnode0 >= n) return;
    for (int i = threadIdx.x; i < SUBN; i += THREADS) lcnt[i] = 0;
    __syncthreads();

    int m = min(bcnt[bucket], CAPB);
    const int* pp = pairs + (size_t)bucket * CAPB;
    for (int i0 = (int)threadIdx.x * 4; i0 < m; i0 += THREADS * 4) {
        int k = min(4, m - i0);
        int v[4];
        if (k == 4) {
            int4 a = *(const int4*)(pp + i0);
            v[0] = a.x; v[1] = a.y; v[2] = a.z; v[3] = a.w;
        } else {
            for (int j = 0; j < k; ++j) v[j] = pp[i0 + j];
        }
#pragma unroll
        for (int j = 0; j < 4; ++j) {
            if (j < k) {
                int dl = v[j] >> 17;               // 9-bit local node
                if ((dl >> 7) == sub) {
                    int ln = dl & (SUBN - 1);
                    int p = atomicAdd(&lcnt[ln], 1);
                    if (p < CAP) slab[ln * CAP + p] = v[j] & 0x1FFFF;
                }
            }
        }
    }
    __syncthreads();

    size_t gbase = (size_t)gnode0 * CAP;
    for (int idx = threadIdx.x; idx < SUBN * CAP; idx += THREADS) {
        int node = gnode0 + idx / CAP;
        if (node < n) csr[gbase + idx] = slab[idx];
    }
    if (threadIdx.x < SUBN) {
        int node = gnode0 + (int)threadIdx.x;
        if (node < n) {
            int dg = min(lcnt[threadIdx.x], CAP);
            cnt[node] = dg;
            float dn = rsqrtf((float)(dg + 1));
            dis[node] = dn;
            const float* xr = x + (size_t)node * 14;
            __half2* o = xs + (size_t)node * 8;
#pragma unroll
            for (int fl = 0; fl < 7; ++fl) {
                float2 v;
                v.x = dn * xr[fl * 2];
                v.y = dn * xr[fl * 2 + 1];
                o[fl] = __float22half2_rn(v);
            }
            o[7] = __float22half2_rn(make_float2(0.f, 0.f));
        }
    }
}

// ---------------- layer-1 CSR gather (f16 rows, packed-f16 accumulate, f32 out) --------------

__global__ __launch_bounds__(THREADS)
void k_gather_l1(const __half2* __restrict__ hw, const int* __restrict__ deg,
                 const int* __restrict__ csr, const float* __restrict__ dis,
                 float* __restrict__ out, int n) {
    constexpr int SG = 4, HPL = 2, RS = 8;
    int tid = blockIdx.x * THREADS + threadIdx.x;
    int node = tid / SG;
    int fl = tid % SG;
    if (node >= n) return;
    size_t o = (size_t)node * CAP;
    int dg = deg[node];
    float dn = dis[node];

    auto loadrow = [&](int s, __half2* r) {
        union { uint2 u; __half2 h[2]; } t;
        t.u = *(const uint2*)(hw + (size_t)s * RS + fl * HPL);
        r[0] = t.h[0]; r[1] = t.h[1];
    };

    float2 self[HPL];
    {
        __half2 r[HPL];
        loadrow(node, r);
#pragma unroll
        for (int q = 0; q < HPL; ++q) {
            self[q] = __half22float2(r[q]);
            self[q].x *= dn; self[q].y *= dn;   // SELF_SCALE
        }
    }

    __half2 z = __float2half2_rn(0.f);
    __half2 c0[HPL], c1[HPL], c2[HPL], c3[HPL];
#pragma unroll
    for (int q = 0; q < HPL; ++q) { c0[q] = z; c1[q] = z; c2[q] = z; c3[q] = z; }

    int base = 0;
    for (; base + SG <= dg; base += SG) {
        int cs = csr[o + base + fl];
#pragma unroll
        for (int t = 0; t < SG; t += 4) {
            int s0 = __shfl(cs, t, SG),     s1 = __shfl(cs, t + 1, SG);
            int s2 = __shfl(cs, t + 2, SG), s3 = __shfl(cs, t + 3, SG);
            __half2 r0[HPL], r1[HPL], r2[HPL], r3[HPL];
            loadrow(s0, r0); loadrow(s1, r1); loadrow(s2, r2); loadrow(s3, r3);
#pragma unroll
            for (int q = 0; q < HPL; ++q) {
                c0[q] = __hadd2(c0[q], r0[q]);
                c1[q] = __hadd2(c1[q], r1[q]);
                c2[q] = __hadd2(c2[q], r2[q]);
                c3[q] = __hadd2(c3[q], r3[q]);
            }
        }
    }
    int rem = dg - base;
    if (rem > 0) {
        int cs = (fl < rem) ? csr[o + base + fl] : 0;
        for (int t = 0; t < rem; ++t) {
            int s = __shfl(cs, t, SG);
            __half2 r[HPL];
            loadrow(s, r);
#pragma unroll
            for (int q = 0; q < HPL; ++q) c0[q] = __hadd2(c0[q], r[q]);
        }
    }

    float* op = out + (size_t)node * 2 * RS + fl * 2 * HPL;
#pragma unroll
    for (int q = 0; q < HPL; ++q) {
        float2 v0 = __half22float2(c0[q]), v1 = __half22float2(c1[q]);
        float2 v2 = __half22float2(c2[q]), v3 = __half22float2(c3[q]);
        op[q * 2 + 0] = self[q].x + (v0.x + v1.x) + (v2.x + v3.x);
        op[q * 2 + 1] = self[q].y + (v0.y + v1.y) + (v2.y + v3.y);
    }
}

// ---------------- fp8 CSR gather (8 B/lane = 8 fp8), f32 accumulate, f16 out -----------------

template<int SG>
__global__ __launch_bounds__(THREADS)
void k_gather_f8(const unsigned char* __restrict__ hw, const int* __restrict__ deg,
                 const int* __restrict__ csr, const float* __restrict__ dis,
                 const float* __restrict__ bias, __half* __restrict__ out, int n) {
    constexpr int RSB = SG * 8;   // row stride bytes
    int tid = blockIdx.x * THREADS + threadIdx.x;
    int node = tid / SG;
    int fl = tid % SG;
    if (node >= n) return;
    size_t o = (size_t)node * CAP;
    int dg = deg[node];
    float dn = dis[node];

    auto loadrow = [&](int s, v2f* r) {
        uint2 u = *(const uint2*)(hw + (size_t)s * RSB + fl * 8);
        r[0] = __builtin_amdgcn_cvt_pk_f32_fp8(u.x, false);
        r[1] = __builtin_amdgcn_cvt_pk_f32_fp8(u.x, true);
        r[2] = __builtin_amdgcn_cvt_pk_f32_fp8(u.y, false);
        r[3] = __builtin_amdgcn_cvt_pk_f32_fp8(u.y, true);
    };

    v2f self[4];
    loadrow(node, self);

    v2f c0[4], c1[4], c2[4], c3[4];
#pragma unroll
    for (int q = 0; q < 4; ++q) { c0[q] = 0.f; c1[q] = 0.f; c2[q] = 0.f; c3[q] = 0.f; }

    int base = 0;
    for (; base + SG <= dg; base += SG) {
        int cs = csr[o + base + fl];
#pragma unroll
        for (int t = 0; t < SG; t += 4) {
            int s0 = __shfl(cs, t, SG),     s1 = __shfl(cs, t + 1, SG);
            int s2 = __shfl(cs, t + 2, SG), s3 = __shfl(cs, t + 3, SG);
            v2f r0[4], r1[4], r2[4], r3[4];
            loadrow(s0, r0); loadrow(s1, r1); loadrow(s2, r2); loadrow(s3, r3);
#pragma unroll
            for (int q = 0; q < 4; ++q) {
                c0[q] += r0[q]; c1[q] += r1[q]; c2[q] += r2[q]; c3[q] += r3[q];
            }
        }
    }
    int rem = dg - base;
    if (rem > 0) {
        int cs = (fl < rem) ? csr[o + base + fl] : 0;
        for (int t = 0; t < rem; ++t) {
            int s = __shfl(cs, t, SG);
            v2f r[4];
            loadrow(s, r);
#pragma unroll
            for (int q = 0; q < 4; ++q) c0[q] += r[q];
        }
    }

    __half* op = out + (size_t)node * SG * 8 + fl * 8;
    union { __half2 h[4]; uint4 u; } p;
#pragma unroll
    for (int q = 0; q < 4; ++q) {
        v2f v = self[q] + (c0[q] + c1[q]) + (c2[q] + c3[q]);
        v *= dn;
        float2 b = ((const float2*)bias)[fl * 4 + q];
        float vx = fmaxf(v.x + b.x, 0.f);
        float vy = fmaxf(v.y + b.y, 0.f);
        p.h[q] = __floats2half2_rn(vx, vy);
    }
    *(uint4*)op = p.u;
}

// ---------------- layer-3 fp8 gather with fused W4 matvec: hw4 = dis*(h3@W4) ----------------

__global__ __launch_bounds__(THREADS)
void k_gather_l3(const unsigned char* __restrict__ hw, const int* __restrict__ deg,
                 const int* __restrict__ csr, const float* __restrict__ dis,
                 const float* __restrict__ b3, const float* __restrict__ W4,
                 float2* __restrict__ hw4, int n) {
    constexpr int SG = 4, RSB = 32;
    __shared__ float Ws4[64];   // 32 x 2
    if (threadIdx.x < 64) Ws4[threadIdx.x] = W4[threadIdx.x];
    __syncthreads();

    int tid = blockIdx.x * THREADS + threadIdx.x;
    int node = tid / SG;
    int fl = tid % SG;
    if (node >= n) return;
    size_t o = (size_t)node * CAP;
    int dg = deg[node];
    float dn = dis[node];

    auto loadrow = [&](int s, v2f* r) {
        uint2 u = *(const uint2*)(hw + (size_t)s * RSB + fl * 8);
        r[0] = __builtin_amdgcn_cvt_pk_f32_fp8(u.x, false);
        r[1] = __builtin_amdgcn_cvt_pk_f32_fp8(u.x, true);
        r[2] = __builtin_amdgcn_cvt_pk_f32_fp8(u.y, false);
        r[3] = __builtin_amdgcn_cvt_pk_f32_fp8(u.y, true);
    };

    v2f self[4];
    loadrow(node, self);

    v2f c0[4], c1[4], c2[4], c3[4];
#pragma unroll
    for (int q = 0; q < 4; ++q) { c0[q] = 0.f; c1[q] = 0.f; c2[q] = 0.f; c3[q] = 0.f; }

    int base = 0;
    for (; base + SG <= dg; base += SG) {
        int cs = csr[o + base + fl];
#pragma unroll
        for (int t = 0; t < SG; t += 4) {
            int s0 = __shfl(cs, t, SG),     s1 = __shfl(cs, t + 1, SG);
            int s2 = __shfl(cs, t + 2, SG), s3 = __shfl(cs, t + 3, SG);
            v2f r0[4], r1[4], r2[4], r3[4];
            loadrow(s0, r0); loadrow(s1, r1); loadrow(s2, r2); loadrow(s3, r3);
#pragma unroll
            for (int q = 0; q < 4; ++q) {
                c0[q] += r0[q]; c1[q] += r1[q]; c2[q] += r2[q]; c3[q] += r3[q];
            }
        }
    }
    int rem = dg - base;
    if (rem > 0) {
        int cs = (fl < rem) ? csr[o + base + fl] : 0;
        for (int t = 0; t < rem; ++t) {
            int s = __shfl(cs, t, SG);
            v2f r[4];
            loadrow(s, r);
#pragma unroll
            for (int q = 0; q < 4; ++q) c0[q] += r[q];
        }
    }

    float p0 = 0.f, p1 = 0.f;
#pragma unroll
    for (int q = 0; q < 4; ++q) {
        v2f v = self[q] + (c0[q] + c1[q]) + (c2[q] + c3[q]);
        v *= dn;
        float2 b = ((const float2*)b3)[fl * 4 + q];
        float vx = fmaxf(v.x + b.x, 0.f);
        float vy = fmaxf(v.y + b.y, 0.f);
        int f = 8 * fl + 2 * q;               // feature index of vx
        p0 += vx * Ws4[f * 2 + 0] + vy * Ws4[(f + 1) * 2 + 0];
        p1 += vx * Ws4[f * 2 + 1] + vy * Ws4[(f + 1) * 2 + 1];
    }
    p0 += __shfl_xor(p0, 1, SG); p0 += __shfl_xor(p0, 2, SG);
    p1 += __shfl_xor(p1, 1, SG); p1 += __shfl_xor(p1, 2, SG);
    if (fl == 0) hw4[node] = make_float2(p0 * dn, p1 * dn);
}

// ---------------- layer-4 phase A: chunked stream -> per-(window,chunk) partials ------------

__global__ __launch_bounds__(THREADS)
void k_l4a(const int* __restrict__ pairs, const int* __restrict__ bcnt,
           const float2* __restrict__ hw4, float2* __restrict__ part, int n) {
    __shared__ float accx[L4WN], accy[L4WN];
    int w     = blockIdx.x / NCH;
    int chunk = blockIdx.x % NCH;
    int bucket = w >> 1;
    int sub    = w & 1;
    int gnode0 = (bucket << BSH) + sub * L4WN;
    if (gnode0 >= n) return;
    for (int i = threadIdx.x; i < L4WN; i += THREADS) { accx[i] = 0.f; accy[i] = 0.f; }
    __syncthreads();

    int m = min(bcnt[bucket], CAPB);
    int c0 = ((chunk * m) / NCH) & ~3;
    int c1 = (chunk == NCH - 1) ? m : (((chunk + 1) * m) / NCH) & ~3;
    const int* pp = pairs + (size_t)bucket * CAPB;
    for (int i0 = c0 + (int)threadIdx.x * 4; i0 < c1; i0 += THREADS * 4) {
        int k = min(4, c1 - i0);
        int v[4];
        if (k == 4) {
            int4 a = *(const int4*)(pp + i0);
            v[0] = a.x; v[1] = a.y; v[2] = a.z; v[3] = a.w;
        } else {
            for (int j = 0; j < k; ++j) v[j] = pp[i0 + j];
        }
        float2 wv[4]; int ln[4]; bool ok[4];
#pragma unroll
        for (int j = 0; j < 4; ++j) {
            int dl = v[j] >> 17;
            ok[j] = (j < k) && ((dl >> 8) == sub);
            ln[j] = dl & (L4WN - 1);
            int s = ok[j] ? (v[j] & 0x1FFFF) : 0;
            wv[j] = hw4[s];
        }
#pragma unroll
        for (int j = 0; j < 4; ++j) {
            if (ok[j]) {
                atomicAdd(&accx[ln[j]], wv[j].x);
                atomicAdd(&accy[ln[j]], wv[j].y);
            }
        }
    }
    __syncthreads();

    float2* op = part + ((size_t)w * NCH + chunk) * L4WN;
    for (int i = threadIdx.x; i < L4WN; i += THREADS)
        op[i] = make_float2(accx[i], accy[i]);
}

// ---------------- layer-4 phase B: sum partials, finalize h4, run-combined pool -------------

__global__ __launch_bounds__(THREADS)
void k_l4b(const float2* __restrict__ part, const float2* __restrict__ hw4,
           const float* __restrict__ dis, const float* __restrict__ b4,
           const int* __restrict__ batch, float* __restrict__ sums,
           float* __restrict__ cnts, int n) {
    __shared__ float h0s[L4WN], h1s[L4WN];
    int w = blockIdx.x;
    int bucket = w >> 1;
    int sub    = w & 1;
    int gnode0 = (bucket << BSH) + sub * L4WN;
    if (gnode0 >= n) return;
    int i = threadIdx.x;                 // THREADS == L4WN
    int node = gnode0 + i;
    if (node < n) {
        const float2* pp = part + (size_t)w * NCH * L4WN;
        float ax = 0.f, ay = 0.f;
#pragma unroll
        for (int ch = 0; ch < NCH; ++ch) {
            float2 p = pp[ch * L4WN + i];
            ax += p.x; ay += p.y;
        }
        float2 self = hw4[node];
        float dn = dis[node];
        h0s[i] = (self.x + ax) * dn + b4[0];
        h1s[i] = (self.y + ay) * dn + b4[1];
    }
    __syncthreads();

    if (threadIdx.x < L4WN / 8) {
        int i0 = threadIdx.x * 8;
        int nvalid = min(gnode0 + L4WN, n) - gnode0;
        int end = min(i0 + 8, nvalid);
        if (i0 < nvalid) {
            int g = batch[gnode0 + i0];
            float v0 = 0.f, v1 = 0.f, c = 0.f;
            for (int q = i0; q < end; ++q) {
                int gi = batch[gnode0 + q];
                if (gi != g) {
                    atomicAdd(&sums[g * 2 + 0], v0);
                    atomicAdd(&sums[g * 2 + 1], v1);
                    atomicAdd(&cnts[g], c);
                    g = gi; v0 = 0.f; v1 = 0.f; c = 0.f;
                }
                v0 += h0s[q];
                v1 += h1s[q];
                c += 1.0f;
            }
            atomicAdd(&sums[g * 2 + 0], v0);
            atomicAdd(&sums[g * 2 + 1], v1);
            atomicAdd(&cnts[g], c);
        }
    }
}

__global__ void k_logsoftmax(const float* __restrict__ sums, const float* __restrict__ cnts,
                             float* __restrict__ out, int ng) {
    int g = blockIdx.x * blockDim.x + threadIdx.x;
    if (g >= ng) return;
    float c = fmaxf(cnts[g], 1.0f);
    float p0 = sums[g * 2 + 0] / c;
    float p1 = sums[g * 2 + 1] / c;
    float m = fmaxf(p0, p1);
    float l = m + logf(expf(p0 - m) + expf(p1 - m));
    out[g * 2 + 0] = p0 - l;
    out[g * 2 + 1] = p1 - l;
}

// ---------------- register-blocked GEMM: 2 nodes x 4 cols per thread ----------------
// OUTM: 0 = f32, 1 = f16, 2 = fp8 (e4m3, HW cvt). IN_T: float or __half.

template<int KW, int K, int KSTR, int FOUT, bool EPI_BIAS_RELU, int OUTM, typename IN_T>
__global__ __launch_bounds__(THREADS)
void k_gemm_rb(const IN_T* __restrict__ in, const float* __restrict__ W,
               const float* __restrict__ dis, const float* __restrict__ bias,
               void* __restrict__ outv, int n) {
    constexpr int CG = FOUT / 4;
    constexpr bool IN_HALF = std::is_same<IN_T, __half>::value;
    constexpr int CH = IN_HALF ? 8 : 4;   // k-chunk per vector load
    __shared__ float Ws[K * FOUT];
    for (int i = threadIdx.x; i < K * FOUT; i += THREADS) {
        int r = i / FOUT;
        Ws[i] = (r < KW) ? W[i] : 0.0f;
    }
    __syncthreads();
    int gid = blockIdx.x * THREADS + threadIdx.x;
    int pair = gid / CG, cg = gid % CG;
    int node0 = pair * 2;
    if (node0 >= n) return;
    bool two = (node0 + 1 < n);
    const IN_T* r0 = in + (size_t)node0 * KSTR;
    const IN_T* r1 = two ? in + (size_t)(node0 + 1) * KSTR : r0;
    const float4* Wf4 = (const float4*)Ws;
    float4 acc0 = {0.f, 0.f, 0.f, 0.f}, acc1 = {0.f, 0.f, 0.f, 0.f};
#pragma unroll
    for (int k0 = 0; k0 < K / CH; ++k0) {
        float xv0[CH], xv1[CH];
        if constexpr (IN_HALF) {
            union { uint4 u; __half2 h[4]; } t0, t1;
            t0.u = ((const uint4*)r0)[k0];
            t1.u = ((const uint4*)r1)[k0];
#pragma unroll
            for (int i = 0; i < 4; ++i) {
                float2 g0 = __half22float2(t0.h[i]);
                float2 g1 = __half22float2(t1.h[i]);
                xv0[2 * i] = g0.x; xv0[2 * i + 1] = g0.y;
                xv1[2 * i] = g1.x; xv1[2 * i + 1] = g1.y;
            }
        } else {
            float4 a0 = ((const float4*)r0)[k0];
            float4 a1 = ((const float4*)r1)[k0];
#pragma unroll
            for (int i = 0; i < 4; ++i) { xv0[i] = (&a0.x)[i]; xv1[i] = (&a1.x)[i]; }
        }
#pragma unroll
        for (int kk = 0; kk < CH; ++kk) {
            float4 wv = Wf4[(k0 * CH + kk) * CG + cg];
            float a = xv0[kk], b = xv1[kk];
            acc0.x += a * wv.x; acc0.y += a * wv.y; acc0.z += a * wv.z; acc0.w += a * wv.w;
            acc1.x += b * wv.x; acc1.y += b * wv.y; acc1.z += b * wv.z; acc1.w += b * wv.w;
        }
    }
    float dn0 = dis[node0];
    float dn1 = two ? dis[node0 + 1] : 0.f;
    acc0.x *= dn0; acc0.y *= dn0; acc0.z *= dn0; acc0.w *= dn0;
    acc1.x *= dn1; acc1.y *= dn1; acc1.z *= dn1; acc1.w *= dn1;
    if (EPI_BIAS_RELU) {
        float4 bv = ((const float4*)bias)[cg];
        acc0.x = fmaxf(acc0.x + bv.x, 0.f); acc0.y = fmaxf(acc0.y + bv.y, 0.f);
        acc0.z = fmaxf(acc0.z + bv.z, 0.f); acc0.w = fmaxf(acc0.w + bv.w, 0.f);
        acc1.x = fmaxf(acc1.x + bv.x, 0.f); acc1.y = fmaxf(acc1.y + bv.y, 0.f);
        acc1.z = fmaxf(acc1.z + bv.z, 0.f); acc1.w = fmaxf(acc1.w + bv.w, 0.f);
    }
    if constexpr (OUTM == 2) {
        unsigned char* ob = (unsigned char*)outv;
        int w0 = 0;
        w0 = __builtin_amdgcn_cvt_pk_fp8_f32(acc0.x, acc0.y, w0, false);
        w0 = __builtin_amdgcn_cvt_pk_fp8_f32(acc0.z, acc0.w, w0, true);
        *(unsigned*)(ob + (size_t)node0 * FOUT + cg * 4) = (unsigned)w0;
        if (two) {
            int w1 = 0;
            w1 = __builtin_amdgcn_cvt_pk_fp8_f32(acc1.x, acc1.y, w1, false);
            w1 = __builtin_amdgcn_cvt_pk_fp8_f32(acc1.z, acc1.w, w1, true);
            *(unsigned*)(ob + (size_t)(node0 + 1) * FOUT + cg * 4) = (unsigned)w1;
        }
    } else if constexpr (OUTM == 1) {
        __half* out = (__half*)outv;
        union { __half2 h[2]; uint2 u; } p0, p1;
        p0.h[0] = __floats2half2_rn(acc0.x, acc0.y);
        p0.h[1] = __floats2half2_rn(acc0.z, acc0.w);
        *(uint2*)(out + (size_t)node0 * FOUT + cg * 4) = p0.u;
        if (two) {
            p1.h[0] = __floats2half2_rn(acc1.x, acc1.y);
            p1.h[1] = __floats2half2_rn(acc1.z, acc1.w);
            *(uint2*)(out + (size_t)(node0 + 1) * FOUT + cg * 4) = p1.u;
        }
    } else {
        float* out = (float*)outv;
        ((float4*)(out + (size_t)node0 * FOUT))[cg] = acc0;
        if (two) ((float4*)(out + (size_t)(node0 + 1) * FOUT))[cg] = acc1;
    }
}

// ---------------- launch ----------------

static inline int nblk(long long t) { return (int)((t + THREADS - 1) / THREADS); }

extern "C" void kernel_launch(void* const* d_in, const int* in_sizes, int n_in,
                              void* d_out, int out_size, void* d_ws, size_t ws_size,
                              hipStream_t stream) {
    const float* x     = (const float*)d_in[0];
    const int*   ei    = (const int*)d_in[1];
    const int*   batch = (const int*)d_in[2];
    const float* W1 = (const float*)d_in[4];
    const float* b1 = (const float*)d_in[5];
    const float* W2 = (const float*)d_in[6];
    const float* b2 = (const float*)d_in[7];
    const float* W3 = (const float*)d_in[8];
    const float* b3 = (const float*)d_in[9];
    const float* W4 = (const float*)d_in[10];
    const float* b4 = (const float*)d_in[11];

    const int n  = in_sizes[0] / 14;
    const int e  = in_sizes[1] / 2;
    const int ng = out_size / 2;
    const int* src = ei;
    const int* dst = ei + e;
    const int nbuck = (n + (1 << BSH) - 1) >> BSH;   // 196 for n=100000
    const int nwin  = nbuck * 2;

    char* ws = (char*)d_ws;
    size_t off_b = 0;
    auto alloc = [&](size_t bytes) -> char* {
        char* p = ws + off_b;
        off_b = (off_b + bytes + 255) & ~(size_t)255;
        return p;
    };
    int*     cnt  = (int*)alloc((size_t)n * 4);                 // in-degree (written by k_scat2)
    char*    zbase = alloc((size_t)MAXB * 4);                   // bcnt | sums | cnts -> one memset
    int*     bcnt = (int*)zbase;
    float*   sums = (float*)alloc((size_t)ng * 2 * 4);
    float*   cnts = (float*)alloc((size_t)ng * 4);
    size_t   zspan = (size_t)((char*)cnts + (size_t)ng * 4 - zbase);
    float*   dis  = (float*)alloc((size_t)n * 4);
    int*     csr  = (int*)alloc((size_t)n * CAP * 4);           // 32 MB CAP-strided rows
    int*     pairs= (int*)alloc((size_t)nbuck * CAPB * 4);      // 14 MB; LIVE until k_l4a
    __half2* xs16 = (__half2*)alloc((size_t)n * 8 * 4);         // n x 16 f16 (3.2 MB, L2-fit)
    float*   agg1 = (float*)alloc((size_t)n * 16 * 4);          // n x 16 f32
    __half*  hbuf16 = (__half*)alloc((size_t)n * 64 * 2);       // h1/h2 f16 (reused)
    unsigned char* hw8 = (unsigned char*)alloc((size_t)n * 64); // hw2' fp8 (reused n x 32 for hw3')
    float*   hw4  = (float*)alloc((size_t)n * 2 * 4);
    float2*  part = (float2*)alloc((size_t)nwin * NCH * L4WN * 8);  // 6.4 MB l4 partials
    (void)ws_size; (void)n_in;

    // --- zero bcnt+sums+cnts; build pairs (replicated-hist); windowed scatter (+dis/xs) ---
    hipMemsetAsync(zbase, 0, zspan, stream);
    k_part<<<nblk(((long long)e + 7) / 8), THREADS, 0, stream>>>(src, dst, bcnt, pairs, e, nbuck);
    k_scat2<<<nbuck * SUBS, THREADS, 0, stream>>>(pairs, bcnt, x, cnt, csr, dis, xs16, n);

    // --- Layer 1 (pre-aggregate at F=16 f16): SG=4; GEMM out f16 ---
    k_gather_l1<<<nblk((long long)n * 4), THREADS, 0, stream>>>(
        xs16, cnt, csr, dis, agg1, n);
    k_gemm_rb<14, 16, 16, 64, true, 1, float><<<nblk((long long)(n / 2 + 1) * 16), THREADS, 0, stream>>>(
        agg1, W1, dis, b1, hbuf16, n);                                // h1 f16

    // --- Layer 2: GEMM f16 in / fp8 out; fp8 gather SG=8, f16 out ---
    k_gemm_rb<64, 64, 64, 64, false, 2, __half><<<nblk((long long)(n / 2 + 1) * 16), THREADS, 0, stream>>>(
        hbuf16, W2, dis, nullptr, hw8, n);                            // hw2' fp8 (64 B rows)
    k_gather_f8<8><<<nblk((long long)n * 8), THREADS, 0, stream>>>(
        hw8, cnt, csr, dis, b2, hbuf16, n);                           // h2 f16 (reuse)

    // --- Layer 3: GEMM f16 in / fp8 out; fp8 gather with fused W4 matvec ---
    k_gemm_rb<64, 64, 64, 32, false, 2, __half><<<nblk((long long)(n / 2 + 1) * 8), THREADS, 0, stream>>>(
        hbuf16, W3, dis, nullptr, hw8, n);                            // hw3' fp8 (32 B rows, 3.2 MB)
    k_gather_l3<<<nblk((long long)n * 4), THREADS, 0, stream>>>(
        hw8, cnt, csr, dis, b3, W4, (float2*)hw4, n);                 // hw4 = dis*(h3@W4)

    // --- Layer 4: chunked partials (3136 blocks) -> finalize+pool (392 blocks) ---
    k_l4a<<<nwin * NCH, THREADS, 0, stream>>>(
        pairs, bcnt, (const float2*)hw4, part, n);
    k_l4b<<<nwin, THREADS, 0, stream>>>(
        part, (const float2*)hw4, dis, b4, batch, sums, cnts, n);
    k_logsoftmax<<<nblk(ng), THREADS, 0, stream>>>(sums, cnts, (float*)d_out, ng);
}